// Round 1
// baseline (899.181 us; speedup 1.0000x reference)
//
#include <hip/hip_runtime.h>
#include <hip/hip_bf16.h>
#include <math.h>

__device__ __forceinline__ float wave_reduce_sum(float v) {
#pragma unroll
  for (int m = 32; m > 0; m >>= 1) v += __shfl_xor(v, m, 64);
  return v;
}
__device__ __forceinline__ float wave_reduce_max(float v) {
#pragma unroll
  for (int m = 32; m > 0; m >>= 1) v = fmaxf(v, __shfl_xor(v, m, 64));
  return v;
}

// ---------------- zero fill (float4) ----------------
__global__ void zero_kernel(float4* __restrict__ p, int n4) {
  int i = blockIdx.x * blockDim.x + threadIdx.x;
  int stride = gridDim.x * blockDim.x;
  float4 z = make_float4(0.f, 0.f, 0.f, 0.f);
  for (; i < n4; i += stride) p[i] = z;
}

__global__ void init_counters_kernel(unsigned int* __restrict__ emax,
                                     int* __restrict__ cnt,
                                     int* __restrict__ cursor, int N) {
  int i = blockIdx.x * blockDim.x + threadIdx.x;
  if (i < N) { emax[i] = 0u; cnt[i] = 0; cursor[i] = 0; }
}

// ---------------- K1: per-node head/tail gates ----------------
__global__ void node_gate_kernel(const float* __restrict__ h,
                                 const float* __restrict__ Wh,
                                 const float* __restrict__ Wt,
                                 float* __restrict__ eh, float* __restrict__ et,
                                 int N) {
  int v = (blockIdx.x * blockDim.x + threadIdx.x) >> 6;
  int lane = threadIdx.x & 63;
  if (v >= N) return;
  float2 hv = *(const float2*)(h + (size_t)v * 128 + 2 * lane);
  float2 wh = *(const float2*)(Wh + 2 * lane);
  float2 wt = *(const float2*)(Wt + 2 * lane);
  float ah = hv.x * wh.x + hv.y * wh.y;
  float at = hv.x * wt.x + hv.y * wt.y;
  ah = wave_reduce_sum(ah);
  at = wave_reduce_sum(at);
  if (lane == 0) {
    eh[v] = tanhf(ah);
    et[v] = tanhf(at);
  }
}

// ---------------- K2: per-edge logits + segment max + degree count ----------------
__global__ void edge_logit_kernel(const float* __restrict__ r,
                                  const float* __restrict__ Wr,
                                  const float* __restrict__ eh,
                                  const float* __restrict__ et,
                                  const int* __restrict__ src,
                                  const int* __restrict__ dst,
                                  float* __restrict__ elog,
                                  unsigned int* __restrict__ emax,
                                  int* __restrict__ cnt, int E) {
  int e = (blockIdx.x * blockDim.x + threadIdx.x) >> 6;
  int lane = threadIdx.x & 63;
  if (e >= E) return;
  float2 rv = *(const float2*)(r + (size_t)e * 128 + 2 * lane);
  float2 wr = *(const float2*)(Wr + 2 * lane);
  float s = rv.x * wr.x + rv.y * wr.y;
  s = wave_reduce_sum(s);
  if (lane == 0) {
    int sv = src[e], dv = dst[e];
    float val = eh[sv] + et[dv] + tanhf(s);
    val = fmaxf(val, 0.f);  // relu; >= 0 so uint-bit atomicMax is order-correct
    elog[e] = val;
    atomicMax(emax + dv, __float_as_uint(val));
    atomicAdd(cnt + dv, 1);
  }
}

// ---------------- K3: exclusive scan of cnt -> rowptr (single block) ----------------
__global__ void scan_kernel(const int* __restrict__ cnt, int* __restrict__ rowptr, int N) {
  __shared__ int sh[1024];
  int t = threadIdx.x;
  int per = (N + 1023) / 1024;
  int base = t * per;
  int run = 0;
  for (int i = 0; i < per; ++i) {
    int idx = base + i;
    if (idx < N) run += cnt[idx];
  }
  sh[t] = run;
  __syncthreads();
  // inclusive Hillis-Steele scan
  for (int off = 1; off < 1024; off <<= 1) {
    int v = sh[t];
    int u = (t >= off) ? sh[t - off] : 0;
    __syncthreads();
    sh[t] = v + u;
    __syncthreads();
  }
  int excl = (t == 0) ? 0 : sh[t - 1];
  int run2 = excl;
  for (int i = 0; i < per; ++i) {
    int idx = base + i;
    if (idx < N) {
      rowptr[idx] = run2;
      run2 += cnt[idx];
    }
  }
  if (t == 0) rowptr[N] = sh[1023];
}

// ---------------- K4: scatter edge ids into CSR ----------------
__global__ void scatter_kernel(const int* __restrict__ dst,
                               const int* __restrict__ rowptr,
                               int* __restrict__ cursor,
                               int* __restrict__ csr, int E) {
  int e = blockIdx.x * blockDim.x + threadIdx.x;
  if (e >= E) return;
  int d = dst[e];
  int slot = atomicAdd(cursor + d, 1);
  csr[rowptr[d] + slot] = e;
}

// ---------------- K5a: ft[v] = sum_e a_e * h[src_e] (wave per node) ----------------
__global__ void ft_kernel(const float* __restrict__ h,
                          const int* __restrict__ src,
                          const int* __restrict__ rowptr,
                          const int* __restrict__ csr,
                          const float* __restrict__ elog,
                          const unsigned int* __restrict__ emax,
                          float* __restrict__ ft, int N) {
  int v = (blockIdx.x * blockDim.x + threadIdx.x) >> 6;
  int lane = threadIdx.x & 63;
  if (v >= N) return;
  int beg = rowptr[v], end = rowptr[v + 1];
  float m = __uint_as_float(emax[v]);
  float dsum = 0.f;
  for (int i = beg + lane; i < end; i += 64) {
    dsum += __expf(elog[csr[i]] - m);
  }
  dsum = wave_reduce_sum(dsum);
  float inv = (end > beg) ? 1.f / dsum : 0.f;
  float a0 = 0.f, a1 = 0.f;
  for (int base = beg; base < end; base += 64) {
    int i = base + lane;
    float av = 0.f;
    int sv = 0;
    if (i < end) {
      int eid = csr[i];
      sv = src[eid];
      av = __expf(elog[eid] - m) * inv;
    }
    int c = min(64, end - base);
    for (int j = 0; j < c; ++j) {
      float a = __shfl(av, j, 64);
      int s = __shfl(sv, j, 64);
      const float* hp = h + (size_t)s * 128;
      a0 += a * hp[lane];
      a1 += a * hp[64 + lane];
    }
  }
  ft[(size_t)v * 128 + lane] = a0;
  ft[(size_t)v * 128 + 64 + lane] = a1;
}

// ---------------- K5b: z = ft @ Wfc^T + b -> L2 normalize -> softmax -> S ----------------
__global__ __launch_bounds__(256) void assign_kernel(const float* __restrict__ ft,
                                                     const float* __restrict__ Wfc,
                                                     const float* __restrict__ bfc,
                                                     float* __restrict__ S, int N) {
  __shared__ float Wt[128 * 128];  // transposed: Wt[d*128 + k] = Wfc[k*128 + d]
  __shared__ float fsh[4][128];
  int t = threadIdx.x;
  for (int i = t; i < 128 * 128; i += 256) {
    int d = i >> 7, k = i & 127;
    Wt[i] = Wfc[k * 128 + d];
  }
  __syncthreads();
  int w = t >> 6, lane = t & 63;
  float b0 = bfc[2 * lane], b1 = bfc[2 * lane + 1];
  int totalWaves = gridDim.x * 4;
  int iters = (N + totalWaves - 1) / totalWaves;
  for (int it = 0; it < iters; ++it) {
    int v = blockIdx.x * 4 + w + it * totalWaves;
    bool active = (v < N);
    float f0 = 0.f, f1 = 0.f;
    if (active) {
      f0 = ft[(size_t)v * 128 + lane];
      f1 = ft[(size_t)v * 128 + 64 + lane];
      fsh[w][lane] = f0;
      fsh[w][64 + lane] = f1;
    }
    __syncthreads();
    if (active) {
      float z0 = b0, z1 = b1;
#pragma unroll 4
      for (int d = 0; d < 128; ++d) {
        float fd = fsh[w][d];
        float2 wv = *(const float2*)(Wt + d * 128 + 2 * lane);
        z0 += fd * wv.x;
        z1 += fd * wv.y;
      }
      float nrm = sqrtf(wave_reduce_sum(z0 * z0 + z1 * z1));
      float dv = fmaxf(nrm, 1e-12f);
      z0 /= dv;
      z1 /= dv;
      float M = wave_reduce_max(fmaxf(z0, z1));
      float e0 = __expf(z0 - M), e1 = __expf(z1 - M);
      float ssum = wave_reduce_sum(e0 + e1);
      float2 sv = make_float2(e0 / ssum, e1 / ssum);
      *(float2*)(S + (size_t)v * 128 + 2 * lane) = sv;
    }
    __syncthreads();
  }
}

// ---------------- K6: P[v] = sum_e S[src_e] (wave per node) ----------------
__global__ void pmat_kernel(const float* __restrict__ S,
                            const int* __restrict__ src,
                            const int* __restrict__ rowptr,
                            const int* __restrict__ csr,
                            float* __restrict__ P, int N) {
  int v = (blockIdx.x * blockDim.x + threadIdx.x) >> 6;
  int lane = threadIdx.x & 63;
  if (v >= N) return;
  int beg = rowptr[v], end = rowptr[v + 1];
  float a0 = 0.f, a1 = 0.f;
  for (int base = beg; base < end; base += 64) {
    int i = base + lane;
    int sv = 0;
    if (i < end) sv = src[csr[i]];
    int c = min(64, end - base);
    for (int j = 0; j < c; ++j) {
      int s = __shfl(sv, j, 64);
      const float* Sp = S + (size_t)s * 128;
      a0 += Sp[lane];
      a1 += Sp[64 + lane];
    }
  }
  P[(size_t)v * 128 + lane] = a0;
  P[(size_t)v * 128 + 64 + lane] = a1;
}

// ---------------- K7: per-graph GEMM out[k][d] = sum_n A[n][k]*B[n][d] ----------------
__global__ __launch_bounds__(256) void pool_gemm_kernel(const float* __restrict__ A,
                                                        const float* __restrict__ Bm,
                                                        float* __restrict__ out,
                                                        long g_stride, int row_stride,
                                                        int npg) {
  int g = blockIdx.y;
  int slab = blockIdx.x;  // 8 slabs of 16 d
  int t = threadIdx.x;
  int k = t & 127;
  int dbase = slab * 16 + (t >> 7) * 8;
  float acc0 = 0.f, acc1 = 0.f, acc2 = 0.f, acc3 = 0.f;
  float acc4 = 0.f, acc5 = 0.f, acc6 = 0.f, acc7 = 0.f;
  const float* Ag = A + (size_t)g * npg * 128;
  const float* Bg = Bm + (size_t)g * npg * 128;
#pragma unroll 4
  for (int n = 0; n < npg; ++n) {
    float a = Ag[(size_t)n * 128 + k];
    const float* br = Bg + (size_t)n * 128 + dbase;
    float4 b0 = *(const float4*)br;
    float4 b1 = *(const float4*)(br + 4);
    acc0 += a * b0.x; acc1 += a * b0.y; acc2 += a * b0.z; acc3 += a * b0.w;
    acc4 += a * b1.x; acc5 += a * b1.y; acc6 += a * b1.z; acc7 += a * b1.w;
  }
  float* orow = out + (size_t)g * g_stride + (size_t)k * row_stride + dbase;
  orow[0] = acc0; orow[1] = acc1; orow[2] = acc2; orow[3] = acc3;
  orow[4] = acc4; orow[5] = acc5; orow[6] = acc6; orow[7] = acc7;
}

extern "C" void kernel_launch(void* const* d_in, const int* in_sizes, int n_in,
                              void* d_out, int out_size, void* d_ws, size_t ws_size,
                              hipStream_t stream) {
  const float* h      = (const float*)d_in[0];
  const float* r      = (const float*)d_in[1];
  const float* W_head = (const float*)d_in[2];
  const float* W_tail = (const float*)d_in[3];
  const float* W_rel  = (const float*)d_in[4];
  const float* W_fc   = (const float*)d_in[5];
  const float* b_fc   = (const float*)d_in[6];
  const int*   src    = (const int*)d_in[7];
  const int*   dst    = (const int*)d_in[8];

  const int B = 32;
  const int D = 128;
  const int N = in_sizes[0] / D;  // 32768
  const int E = in_sizes[7];      // 1048576
  const int npg = N / B;          // 1024

  // workspace layout
  char* wsb = (char*)d_ws;
  size_t off = 0;
  auto alloc = [&](size_t bytes) -> void* {
    void* p = wsb + off;
    off = (off + bytes + 255) & ~(size_t)255;
    return p;
  };
  float*        eh     = (float*)alloc((size_t)N * 4);
  float*        et     = (float*)alloc((size_t)N * 4);
  unsigned int* emax   = (unsigned int*)alloc((size_t)N * 4);
  int*          cnt    = (int*)alloc((size_t)N * 4);
  int*          cursor = (int*)alloc((size_t)N * 4);
  int*          rowptr = (int*)alloc((size_t)(N + 1) * 4);
  float*        elog   = (float*)alloc((size_t)E * 4);
  int*          csr    = (int*)alloc((size_t)E * 4);
  float*        ft     = (float*)alloc((size_t)N * 128 * 4);
  float*        S      = (float*)alloc((size_t)N * 128 * 4);
  float*        P      = (float*)alloc((size_t)N * 128 * 4);
  (void)ws_size;

  // zero whole output (adj is block-diagonal: off-diag must be 0)
  zero_kernel<<<2048, 256, 0, stream>>>((float4*)d_out, out_size / 4);
  init_counters_kernel<<<(N + 255) / 256, 256, 0, stream>>>(emax, cnt, cursor, N);

  node_gate_kernel<<<N / 4, 256, 0, stream>>>(h, W_head, W_tail, eh, et, N);
  edge_logit_kernel<<<E / 4, 256, 0, stream>>>(r, W_rel, eh, et, src, dst, elog, emax, cnt, E);
  scan_kernel<<<1, 1024, 0, stream>>>(cnt, rowptr, N);
  scatter_kernel<<<(E + 255) / 256, 256, 0, stream>>>(dst, rowptr, cursor, csr, E);
  ft_kernel<<<N / 4, 256, 0, stream>>>(h, src, rowptr, csr, elog, emax, ft, N);
  assign_kernel<<<512, 256, 0, stream>>>(ft, W_fc, b_fc, S, N);
  pmat_kernel<<<N / 4, 256, 0, stream>>>(S, src, rowptr, csr, P, N);

  // h_pool: out offset after adj (B*K x B*K), layout [B][K][D]
  float* out_f = (float*)d_out;
  const long adj_elems = (long)(B * 128) * (B * 128);
  pool_gemm_kernel<<<dim3(8, B), 256, 0, stream>>>(S, h, out_f + adj_elems,
                                                   (long)128 * 128, 128, npg);
  // adj blocks: out[(g*128+k)*4096 + g*128 + l]
  pool_gemm_kernel<<<dim3(8, B), 256, 0, stream>>>(P, S, out_f,
                                                   (long)(128 * (B * 128) + 128), B * 128, npg);
}

// Round 2
// 622.603 us; speedup vs baseline: 1.4442x; 1.4442x over previous
//
#include <hip/hip_runtime.h>
#include <hip/hip_bf16.h>
#include <math.h>

__device__ __forceinline__ float wave_reduce_sum(float v) {
#pragma unroll
  for (int m = 32; m > 0; m >>= 1) v += __shfl_xor(v, m, 64);
  return v;
}
__device__ __forceinline__ float wave_reduce_max(float v) {
#pragma unroll
  for (int m = 32; m > 0; m >>= 1) v = fmaxf(v, __shfl_xor(v, m, 64));
  return v;
}

// ---------------- zero fill (float4) ----------------
__global__ void zero_kernel(float4* __restrict__ p, int n4) {
  int i = blockIdx.x * blockDim.x + threadIdx.x;
  int stride = gridDim.x * blockDim.x;
  float4 z = make_float4(0.f, 0.f, 0.f, 0.f);
  for (; i < n4; i += stride) p[i] = z;
}

__global__ void init_counters_kernel(unsigned int* __restrict__ emax,
                                     int* __restrict__ cnt,
                                     int* __restrict__ cursor, int N) {
  int i = blockIdx.x * blockDim.x + threadIdx.x;
  if (i < N) { emax[i] = 0u; cnt[i] = 0; cursor[i] = 0; }
}

// ---------------- K1: per-node head/tail gates ----------------
__global__ void node_gate_kernel(const float* __restrict__ h,
                                 const float* __restrict__ Wh,
                                 const float* __restrict__ Wt,
                                 float* __restrict__ eh, float* __restrict__ et,
                                 int N) {
  int v = (blockIdx.x * blockDim.x + threadIdx.x) >> 6;
  int lane = threadIdx.x & 63;
  if (v >= N) return;
  float2 hv = *(const float2*)(h + (size_t)v * 128 + 2 * lane);
  float2 wh = *(const float2*)(Wh + 2 * lane);
  float2 wt = *(const float2*)(Wt + 2 * lane);
  float ah = hv.x * wh.x + hv.y * wh.y;
  float at = hv.x * wt.x + hv.y * wt.y;
  ah = wave_reduce_sum(ah);
  at = wave_reduce_sum(at);
  if (lane == 0) {
    eh[v] = tanhf(ah);
    et[v] = tanhf(at);
  }
}

// ---------------- K2: per-edge logits + segment max + degree count ----------------
// 32-lane group per edge, float4 loads, 4 edges per group => 8 edges/wave.
__global__ __launch_bounds__(256) void edge_logit_kernel(
    const float* __restrict__ r, const float* __restrict__ Wr,
    const float* __restrict__ eh, const float* __restrict__ et,
    const int* __restrict__ src, const int* __restrict__ dst,
    float* __restrict__ elog, unsigned int* __restrict__ emax,
    int* __restrict__ cnt, int E) {
  int wid = (blockIdx.x * blockDim.x + threadIdx.x) >> 6;
  int grp = (threadIdx.x >> 5) & 1;
  int gl = threadIdx.x & 31;
  int ebase = wid * 8 + grp * 4;
  if (ebase >= E) return;
  const float4* r4 = (const float4*)r;
  float4 w4 = ((const float4*)Wr)[gl];
  size_t rb = (size_t)ebase * 32 + gl;
  float4 v0 = r4[rb];
  float4 v1 = r4[rb + 32];
  float4 v2 = r4[rb + 64];
  float4 v3 = r4[rb + 96];
  float s0 = v0.x * w4.x + v0.y * w4.y + v0.z * w4.z + v0.w * w4.w;
  float s1 = v1.x * w4.x + v1.y * w4.y + v1.z * w4.z + v1.w * w4.w;
  float s2 = v2.x * w4.x + v2.y * w4.y + v2.z * w4.z + v2.w * w4.w;
  float s3 = v3.x * w4.x + v3.y * w4.y + v3.z * w4.z + v3.w * w4.w;
#pragma unroll
  for (int m = 16; m > 0; m >>= 1) {
    s0 += __shfl_xor(s0, m, 32);
    s1 += __shfl_xor(s1, m, 32);
    s2 += __shfl_xor(s2, m, 32);
    s3 += __shfl_xor(s3, m, 32);
  }
  if (gl < 4) {
    int e = ebase + gl;
    float s = (gl == 0) ? s0 : (gl == 1) ? s1 : (gl == 2) ? s2 : s3;
    float t = 1.f - 2.f / (__expf(2.f * s) + 1.f);  // tanh(s)
    int dv = dst[e];
    float val = fmaxf(eh[src[e]] + et[dv] + t, 0.f);  // relu >= 0
    elog[e] = val;
    atomicMax(emax + dv, __float_as_uint(val));
    atomicAdd(cnt + dv, 1);
  }
}

// ---------------- K3: exclusive scan of cnt -> rowptr (single block) ----------------
__global__ void scan_kernel(const int* __restrict__ cnt, int* __restrict__ rowptr, int N) {
  __shared__ int sh[1024];
  int t = threadIdx.x;
  int per = (N + 1023) / 1024;
  int base = t * per;
  int run = 0;
  for (int i = 0; i < per; ++i) {
    int idx = base + i;
    if (idx < N) run += cnt[idx];
  }
  sh[t] = run;
  __syncthreads();
  for (int off = 1; off < 1024; off <<= 1) {
    int v = sh[t];
    int u = (t >= off) ? sh[t - off] : 0;
    __syncthreads();
    sh[t] = v + u;
    __syncthreads();
  }
  int excl = (t == 0) ? 0 : sh[t - 1];
  int run2 = excl;
  for (int i = 0; i < per; ++i) {
    int idx = base + i;
    if (idx < N) {
      rowptr[idx] = run2;
      run2 += cnt[idx];
    }
  }
  if (t == 0) rowptr[N] = sh[1023];
}

// ---------------- K4: scatter edge ids into CSR ----------------
__global__ void scatter_kernel(const int* __restrict__ dst,
                               const int* __restrict__ rowptr,
                               int* __restrict__ cursor,
                               int* __restrict__ csr, int E) {
  int e = blockIdx.x * blockDim.x + threadIdx.x;
  if (e >= E) return;
  int d = dst[e];
  int slot = atomicAdd(cursor + d, 1);
  csr[rowptr[d] + slot] = e;
}

// ---------------- K5a: ft[v] = sum_e a_e * h[src_e] (32-lane group per node) ----------------
__global__ __launch_bounds__(256) void ft_kernel(
    const float* __restrict__ h, const int* __restrict__ src,
    const int* __restrict__ rowptr, const int* __restrict__ csr,
    const float* __restrict__ elog, const unsigned int* __restrict__ emax,
    float* __restrict__ ft, int N) {
  int wid = (blockIdx.x * blockDim.x + threadIdx.x) >> 6;
  int grp = (threadIdx.x >> 5) & 1;
  int gl = threadIdx.x & 31;
  int v = wid * 2 + grp;
  if (v >= N) return;
  int beg = rowptr[v], end = rowptr[v + 1];
  float m = __uint_as_float(emax[v]);
  float dsum = 0.f;
  for (int i = beg + gl; i < end; i += 32) dsum += __expf(elog[csr[i]] - m);
#pragma unroll
  for (int mm = 16; mm > 0; mm >>= 1) dsum += __shfl_xor(dsum, mm, 32);
  float inv = (end > beg) ? 1.f / dsum : 0.f;
  const float4* h4 = (const float4*)h;
  float4 acc = make_float4(0.f, 0.f, 0.f, 0.f);
  for (int base = beg; base < end; base += 32) {
    int i = base + gl;
    float av = 0.f;
    int sv = 0;
    if (i < end) {
      int eid = csr[i];
      sv = src[eid];
      av = __expf(elog[eid] - m) * inv;
    }
    int c = min(32, end - base);
    int c4 = (c + 3) & ~3;
    for (int j = 0; j < c4; j += 4) {
#pragma unroll
      for (int jj = 0; jj < 4; ++jj) {
        float a = __shfl(av, j + jj, 32);
        int s = __shfl(sv, j + jj, 32);
        float4 hv = h4[(size_t)s * 32 + gl];
        acc.x += a * hv.x;
        acc.y += a * hv.y;
        acc.z += a * hv.z;
        acc.w += a * hv.w;
      }
    }
  }
  ((float4*)ft)[(size_t)v * 32 + gl] = acc;
}

// ---------------- K5b: z = ft @ Wfc^T + b -> L2 normalize -> softmax -> S ----------------
__global__ __launch_bounds__(256) void assign_kernel(const float* __restrict__ ft,
                                                     const float* __restrict__ Wfc,
                                                     const float* __restrict__ bfc,
                                                     float* __restrict__ S, int N) {
  __shared__ float Wt[128 * 128];  // transposed: Wt[d*128 + k] = Wfc[k*128 + d]
  __shared__ float fsh[4][128];
  int t = threadIdx.x;
  for (int i = t; i < 128 * 128; i += 256) {
    int d = i >> 7, k = i & 127;
    Wt[i] = Wfc[k * 128 + d];
  }
  __syncthreads();
  int w = t >> 6, lane = t & 63;
  float b0 = bfc[2 * lane], b1 = bfc[2 * lane + 1];
  int totalWaves = gridDim.x * 4;
  int iters = (N + totalWaves - 1) / totalWaves;
  for (int it = 0; it < iters; ++it) {
    int v = blockIdx.x * 4 + w + it * totalWaves;
    bool active = (v < N);
    if (active) {
      fsh[w][lane] = ft[(size_t)v * 128 + lane];
      fsh[w][64 + lane] = ft[(size_t)v * 128 + 64 + lane];
    }
    __syncthreads();
    if (active) {
      float z0 = b0, z1 = b1;
#pragma unroll 4
      for (int d = 0; d < 128; ++d) {
        float fd = fsh[w][d];
        float2 wv = *(const float2*)(Wt + d * 128 + 2 * lane);
        z0 += fd * wv.x;
        z1 += fd * wv.y;
      }
      float nrm = sqrtf(wave_reduce_sum(z0 * z0 + z1 * z1));
      float dv = fmaxf(nrm, 1e-12f);
      z0 /= dv;
      z1 /= dv;
      float M = wave_reduce_max(fmaxf(z0, z1));
      float e0 = __expf(z0 - M), e1 = __expf(z1 - M);
      float ssum = wave_reduce_sum(e0 + e1);
      float2 sv = make_float2(e0 / ssum, e1 / ssum);
      *(float2*)(S + (size_t)v * 128 + 2 * lane) = sv;
    }
    __syncthreads();
  }
}

// ---------------- K6: P[v] = sum_e S[src_e] (32-lane group per node) ----------------
__global__ __launch_bounds__(256) void pmat_kernel(
    const float* __restrict__ S, const int* __restrict__ src,
    const int* __restrict__ rowptr, const int* __restrict__ csr,
    float* __restrict__ P, int N) {
  int wid = (blockIdx.x * blockDim.x + threadIdx.x) >> 6;
  int grp = (threadIdx.x >> 5) & 1;
  int gl = threadIdx.x & 31;
  int v = wid * 2 + grp;
  if (v >= N) return;
  int beg = rowptr[v], end = rowptr[v + 1];
  const float4* S4 = (const float4*)S;
  float4 acc = make_float4(0.f, 0.f, 0.f, 0.f);
  for (int base = beg; base < end; base += 32) {
    int i = base + gl;
    float av = 0.f;
    int sv = 0;
    if (i < end) {
      sv = src[csr[i]];
      av = 1.f;
    }
    int c = min(32, end - base);
    int c4 = (c + 3) & ~3;
    for (int j = 0; j < c4; j += 4) {
#pragma unroll
      for (int jj = 0; jj < 4; ++jj) {
        float a = __shfl(av, j + jj, 32);
        int s = __shfl(sv, j + jj, 32);
        float4 hv = S4[(size_t)s * 32 + gl];
        acc.x += a * hv.x;
        acc.y += a * hv.y;
        acc.z += a * hv.z;
        acc.w += a * hv.w;
      }
    }
  }
  ((float4*)P)[(size_t)v * 32 + gl] = acc;
}

// ---------------- K7: per-graph GEMM out[k][d] = sum_n A[n][k]*B[n][d] ----------------
__global__ __launch_bounds__(256) void pool_gemm_kernel(const float* __restrict__ A,
                                                        const float* __restrict__ Bm,
                                                        float* __restrict__ out,
                                                        long g_stride, int row_stride,
                                                        int npg) {
  int g = blockIdx.y;
  int slab = blockIdx.x;  // 8 slabs of 16 d
  int t = threadIdx.x;
  int k = t & 127;
  int dbase = slab * 16 + (t >> 7) * 8;
  float acc0 = 0.f, acc1 = 0.f, acc2 = 0.f, acc3 = 0.f;
  float acc4 = 0.f, acc5 = 0.f, acc6 = 0.f, acc7 = 0.f;
  const float* Ag = A + (size_t)g * npg * 128;
  const float* Bg = Bm + (size_t)g * npg * 128;
#pragma unroll 4
  for (int n = 0; n < npg; ++n) {
    float a = Ag[(size_t)n * 128 + k];
    const float* br = Bg + (size_t)n * 128 + dbase;
    float4 b0 = *(const float4*)br;
    float4 b1 = *(const float4*)(br + 4);
    acc0 += a * b0.x; acc1 += a * b0.y; acc2 += a * b0.z; acc3 += a * b0.w;
    acc4 += a * b1.x; acc5 += a * b1.y; acc6 += a * b1.z; acc7 += a * b1.w;
  }
  float* orow = out + (size_t)g * g_stride + (size_t)k * row_stride + dbase;
  orow[0] = acc0; orow[1] = acc1; orow[2] = acc2; orow[3] = acc3;
  orow[4] = acc4; orow[5] = acc5; orow[6] = acc6; orow[7] = acc7;
}

extern "C" void kernel_launch(void* const* d_in, const int* in_sizes, int n_in,
                              void* d_out, int out_size, void* d_ws, size_t ws_size,
                              hipStream_t stream) {
  const float* h      = (const float*)d_in[0];
  const float* r      = (const float*)d_in[1];
  const float* W_head = (const float*)d_in[2];
  const float* W_tail = (const float*)d_in[3];
  const float* W_rel  = (const float*)d_in[4];
  const float* W_fc   = (const float*)d_in[5];
  const float* b_fc   = (const float*)d_in[6];
  const int*   src    = (const int*)d_in[7];
  const int*   dst    = (const int*)d_in[8];

  const int B = 32;
  const int D = 128;
  const int N = in_sizes[0] / D;  // 32768
  const int E = in_sizes[7];      // 1048576
  const int npg = N / B;          // 1024

  char* wsb = (char*)d_ws;
  size_t off = 0;
  auto alloc = [&](size_t bytes) -> void* {
    void* p = wsb + off;
    off = (off + bytes + 255) & ~(size_t)255;
    return p;
  };
  float*        eh     = (float*)alloc((size_t)N * 4);
  float*        et     = (float*)alloc((size_t)N * 4);
  unsigned int* emax   = (unsigned int*)alloc((size_t)N * 4);
  int*          cnt    = (int*)alloc((size_t)N * 4);
  int*          cursor = (int*)alloc((size_t)N * 4);
  int*          rowptr = (int*)alloc((size_t)(N + 1) * 4);
  float*        elog   = (float*)alloc((size_t)E * 4);
  int*          csr    = (int*)alloc((size_t)E * 4);
  float*        ft     = (float*)alloc((size_t)N * 128 * 4);
  float*        S      = (float*)alloc((size_t)N * 128 * 4);
  float*        P      = (float*)alloc((size_t)N * 128 * 4);
  (void)ws_size;

  zero_kernel<<<2048, 256, 0, stream>>>((float4*)d_out, out_size / 4);
  init_counters_kernel<<<(N + 255) / 256, 256, 0, stream>>>(emax, cnt, cursor, N);

  node_gate_kernel<<<N / 4, 256, 0, stream>>>(h, W_head, W_tail, eh, et, N);
  // 8 edges per wave, 4 waves per block
  edge_logit_kernel<<<E / 32, 256, 0, stream>>>(r, W_rel, eh, et, src, dst, elog, emax, cnt, E);
  scan_kernel<<<1, 1024, 0, stream>>>(cnt, rowptr, N);
  scatter_kernel<<<(E + 255) / 256, 256, 0, stream>>>(dst, rowptr, cursor, csr, E);
  // 2 nodes per wave -> N/2 waves -> N/8 blocks
  ft_kernel<<<N / 8, 256, 0, stream>>>(h, src, rowptr, csr, elog, emax, ft, N);
  assign_kernel<<<512, 256, 0, stream>>>(ft, W_fc, b_fc, S, N);
  pmat_kernel<<<N / 8, 256, 0, stream>>>(S, src, rowptr, csr, P, N);

  float* out_f = (float*)d_out;
  const long adj_elems = (long)(B * 128) * (B * 128);
  pool_gemm_kernel<<<dim3(8, B), 256, 0, stream>>>(S, h, out_f + adj_elems,
                                                   (long)128 * 128, 128, npg);
  pool_gemm_kernel<<<dim3(8, B), 256, 0, stream>>>(P, S, out_f,
                                                   (long)(128 * (B * 128) + 128), B * 128, npg);
}